// Round 1
// baseline (397.760 us; speedup 1.0000x reference)
//
#include <hip/hip_runtime.h>
#include <hip/hip_bf16.h>

typedef float  f32x4  __attribute__((ext_vector_type(4)));
typedef short  bf16x8 __attribute__((ext_vector_type(8)));

__device__ __forceinline__ ushort f2b(float f) {
  union { float f; unsigned u; } x; x.f = f;
  unsigned r = x.u + 0x7fffu + ((x.u >> 16) & 1u);   // RNE
  return (ushort)(r >> 16);
}

__device__ __forceinline__ f32x4 fzero() {
  f32x4 z; z[0] = 0.f; z[1] = 0.f; z[2] = 0.f; z[3] = 0.f; return z;
}

__device__ __forceinline__ void gld_lds16(const ushort* g, ushort* l) {
  __builtin_amdgcn_global_load_lds(g, l, 16, 0, 0);
}

// ---------------- fp32 -> bf16 convert ----------------
__global__ __launch_bounds__(256) void f2bf_kernel(const float* __restrict__ in,
                                                   ushort* __restrict__ out, int n4) {
  int idx = blockIdx.x * 256 + threadIdx.x;
  int stride = gridDim.x * 256;
  for (int i = idx; i < n4; i += stride) {
    float4 v = reinterpret_cast<const float4*>(in)[i];
    ushort4 o;
    o.x = f2b(v.x); o.y = f2b(v.y); o.z = f2b(v.z); o.w = f2b(v.w);
    reinterpret_cast<ushort4*>(out)[i] = o;
  }
}

// ---------------- C[i,j] = sum_k A[i,k]*B[j,k] + bias[j]  (B^T GEMM) ----------------
// m97 structure: 128x128 tile, BK=32, 4 waves, each wave 64x64 (4x4 16x16 frags)
__global__ __launch_bounds__(256) void gemm_bt(
    const ushort* __restrict__ A,    // [M,K] bf16
    const ushort* __restrict__ B,    // [N,K] bf16
    const float*  __restrict__ bias, // [N]
    float*  __restrict__ Cf,         // fp32 out (or null)
    ushort* __restrict__ Cb,         // bf16 out (or null)
    int M, int N, int K) {
  __shared__ ushort As[128 * 32];
  __shared__ ushort Bs[128 * 32];
  const int tid  = threadIdx.x;
  const int lane = tid & 63;
  const int wave = tid >> 6;
  const int wr = (wave >> 1) << 6;      // wave row offset (0/64)
  const int wc = (wave & 1) << 6;       // wave col offset (0/64)
  const int fr  = lane & 15;            // fragment row/col
  const int fk8 = (lane >> 4) << 3;     // k offset within fragment

  const size_t rowA = (size_t)blockIdx.y * 128;
  const size_t rowB = (size_t)blockIdx.x * 128;
  const ushort* Ag = A + rowA * K;
  const ushort* Bg = B + rowB * K;

  // staging: 512 chunks of 16B per 128x32 tile; 4 chunks per row
  const int c0 = tid, c1 = tid + 256;
  const size_t a0 = (size_t)(c0 >> 2) * K + (size_t)((c0 & 3) << 3);
  const size_t a1 = (size_t)(c1 >> 2) * K + (size_t)((c1 & 3) << 3);

  f32x4 acc[4][4];
#pragma unroll
  for (int m = 0; m < 4; ++m)
#pragma unroll
    for (int n = 0; n < 4; ++n) acc[m][n] = fzero();

  for (int k0 = 0; k0 < K; k0 += 32) {
    __syncthreads();
    gld_lds16(Ag + a0 + k0, &As[wave * 512]);
    gld_lds16(Ag + a1 + k0, &As[2048 + wave * 512]);
    gld_lds16(Bg + a0 + k0, &Bs[wave * 512]);
    gld_lds16(Bg + a1 + k0, &Bs[2048 + wave * 512]);
    asm volatile("s_waitcnt vmcnt(0)" ::: "memory");
    __syncthreads();

    bf16x8 af[4], bfv[4];
#pragma unroll
    for (int m = 0; m < 4; ++m)
      af[m] = *reinterpret_cast<const bf16x8*>(&As[(wr + m * 16 + fr) * 32 + fk8]);
#pragma unroll
    for (int n = 0; n < 4; ++n)
      bfv[n] = *reinterpret_cast<const bf16x8*>(&Bs[(wc + n * 16 + fr) * 32 + fk8]);
#pragma unroll
    for (int m = 0; m < 4; ++m)
#pragma unroll
      for (int n = 0; n < 4; ++n)
        acc[m][n] = __builtin_amdgcn_mfma_f32_16x16x32_bf16(af[m], bfv[n], acc[m][n], 0, 0, 0);
  }

  // epilogue: C/D layout col=lane&15, row=(lane>>4)*4+r  [m89 verified]
  const int orow = (lane >> 4) << 2;
#pragma unroll
  for (int m = 0; m < 4; ++m) {
#pragma unroll
    for (int n = 0; n < 4; ++n) {
      size_t gc = rowB + wc + n * 16 + fr;
      float bv = bias[gc];
#pragma unroll
      for (int r = 0; r < 4; ++r) {
        size_t gr = rowA + wr + m * 16 + orow + r;
        float v = acc[m][n][r] + bv;
        if (Cf) Cf[gr * N + gc] = v;
        else    Cb[gr * N + gc] = f2b(v);
      }
    }
  }
}

// ---------------- flash attention (no mask), Q/K/V bf16 [B*T, C] head-interleaved ----------------
// grid (32 qtiles, 64 b*h), 4 waves; wave owns 16 q-rows; KV tile = 64 rows
__global__ __launch_bounds__(256) void attn_kernel(
    const ushort* __restrict__ Qb, const ushort* __restrict__ Kb,
    const ushort* __restrict__ Vb, ushort* __restrict__ Yb) {
  const int T = 2048, Cdim = 1024, D = 64;
  __shared__ ushort Ks[64 * 64];      // [j][d], data XOR-swizzled via pre-swizzled global src
  __shared__ ushort Vt[64 * 64];      // [d][j], swizzled
  __shared__ ushort Ps[4][16 * 64];   // per-wave P tile [i][j], swizzled

  const int tid  = threadIdx.x;
  const int lane = tid & 63;
  const int wave = tid >> 6;
  const int fr   = lane & 15;
  const int fk8  = (lane >> 4) << 3;
  const int b = blockIdx.y >> 4;
  const int h = blockIdx.y & 15;
  const size_t rowbase = (size_t)b * T;
  const int cbase = h * D;

  // Q fragments (A-operand): row = lane&15, k = (lane>>4)*8, two K-steps over D=64
  const int qrow = blockIdx.x * 64 + wave * 16 + fr;
  bf16x8 qf[2];
#pragma unroll
  for (int kk = 0; kk < 2; ++kk)
    qf[kk] = *reinterpret_cast<const bf16x8*>(
        &Qb[(rowbase + qrow) * Cdim + cbase + kk * 32 + fk8]);

  f32x4 yacc[4];
#pragma unroll
  for (int n = 0; n < 4; ++n) yacc[n] = fzero();
  float mrow[4] = {-__builtin_inff(), -__builtin_inff(), -__builtin_inff(), -__builtin_inff()};
  float lrow[4] = {0.f, 0.f, 0.f, 0.f};

  // staging chunks: 512 x 16B, 8 chunks per 64-elem row
  const int c0 = tid, c1 = tid + 256;
  const int r0 = c0 >> 3, cc0 = c0 & 7;
  const int r1 = c1 >> 3, cc1 = c1 & 7;

  for (int kt = 0; kt < 32; ++kt) {
    const int jb = kt * 64;
    __syncthreads();
    // K tile: linear LDS dest + inverse-swizzled global source (rule #21)
    gld_lds16(&Kb[(rowbase + jb + r0) * Cdim + cbase + ((cc0 ^ (r0 & 7)) << 3)], &Ks[wave * 512]);
    gld_lds16(&Kb[(rowbase + jb + r1) * Cdim + cbase + ((cc1 ^ (r1 & 7)) << 3)], &Ks[2048 + wave * 512]);
    // V tile -> regs -> transposed+swizzled LDS
    uint4 v0 = *reinterpret_cast<const uint4*>(&Vb[(rowbase + jb + r0) * Cdim + cbase + (cc0 << 3)]);
    uint4 v1 = *reinterpret_cast<const uint4*>(&Vb[(rowbase + jb + r1) * Cdim + cbase + (cc1 << 3)]);
    {
      const ushort* p0 = reinterpret_cast<const ushort*>(&v0);
      const ushort* p1 = reinterpret_cast<const ushort*>(&v1);
#pragma unroll
      for (int i = 0; i < 8; ++i) {
        int d0 = (cc0 << 3) + i;
        int g0 = ((d0 >> 3) ^ d0) & 7;
        Vt[d0 * 64 + (r0 ^ (g0 << 3))] = p0[i];
        int d1 = (cc1 << 3) + i;
        int g1 = ((d1 >> 3) ^ d1) & 7;
        Vt[d1 * 64 + (r1 ^ (g1 << 3))] = p1[i];
      }
    }
    asm volatile("s_waitcnt vmcnt(0)" ::: "memory");
    __syncthreads();

    // S = Q K^T (per wave: 16 x 64)
    f32x4 s[4];
#pragma unroll
    for (int n = 0; n < 4; ++n) s[n] = fzero();
#pragma unroll
    for (int n = 0; n < 4; ++n) {
      int krow = n * 16 + fr;
#pragma unroll
      for (int kk = 0; kk < 2; ++kk) {
        bf16x8 kf = *reinterpret_cast<const bf16x8*>(
            &Ks[krow * 64 + ((kk * 32 + fk8) ^ ((fr & 7) << 3))]);
        s[n] = __builtin_amdgcn_mfma_f32_16x16x32_bf16(qf[kk], kf, s[n], 0, 0, 0);
      }
    }
#pragma unroll
    for (int n = 0; n < 4; ++n) s[n] = s[n] * 0.125f;   // 1/sqrt(64)

    // online softmax, rows i = (lane>>4)*4 + r, cols across lanes sharing lane>>4
#pragma unroll
    for (int r = 0; r < 4; ++r) {
      float mx = fmaxf(fmaxf(s[0][r], s[1][r]), fmaxf(s[2][r], s[3][r]));
      mx = fmaxf(mx, __shfl_xor(mx, 1));
      mx = fmaxf(mx, __shfl_xor(mx, 2));
      mx = fmaxf(mx, __shfl_xor(mx, 4));
      mx = fmaxf(mx, __shfl_xor(mx, 8));
      float mnew  = fmaxf(mrow[r], mx);
      float alpha = __expf(mrow[r] - mnew);
      mrow[r] = mnew;
      const int prow = ((lane >> 4) << 2) + r;
      float psum = 0.f;
#pragma unroll
      for (int n = 0; n < 4; ++n) {
        float p = __expf(s[n][r] - mnew);
        psum += p;
        Ps[wave][prow * 64 + ((n * 16 + fr) ^ ((prow & 7) << 3))] = f2b(p);
      }
      psum += __shfl_xor(psum, 1);
      psum += __shfl_xor(psum, 2);
      psum += __shfl_xor(psum, 4);
      psum += __shfl_xor(psum, 8);
      lrow[r] = lrow[r] * alpha + psum;
#pragma unroll
      for (int n = 0; n < 4; ++n) yacc[n][r] *= alpha;
    }

    // Y += P V   (A = P from per-wave LDS, B = Vt)
#pragma unroll
    for (int kk = 0; kk < 2; ++kk) {
      bf16x8 pa = *reinterpret_cast<const bf16x8*>(
          &Ps[wave][fr * 64 + ((kk * 32 + fk8) ^ ((fr & 7) << 3))]);
#pragma unroll
      for (int n = 0; n < 4; ++n) {
        int d = n * 16 + fr;
        int g = ((d >> 3) ^ d) & 7;
        bf16x8 vf = *reinterpret_cast<const bf16x8*>(
            &Vt[d * 64 + ((kk * 32 + fk8) ^ (g << 3))]);
        yacc[n] = __builtin_amdgcn_mfma_f32_16x16x32_bf16(pa, vf, yacc[n], 0, 0, 0);
      }
    }
  }

  // epilogue: divide by row sum, write bf16 head-interleaved
  const int orow = (lane >> 4) << 2;
#pragma unroll
  for (int n = 0; n < 4; ++n) {
#pragma unroll
    for (int r = 0; r < 4; ++r) {
      float v = yacc[n][r] / lrow[r];
      size_t row = rowbase + (size_t)blockIdx.x * 64 + wave * 16 + orow + r;
      Yb[row * Cdim + cbase + n * 16 + fr] = f2b(v);
    }
  }
}

extern "C" void kernel_launch(void* const* d_in, const int* in_sizes, int n_in,
                              void* d_out, int out_size, void* d_ws, size_t ws_size,
                              hipStream_t stream) {
  const float* x  = (const float*)d_in[0];
  const float* Wq = (const float*)d_in[1];
  const float* bq = (const float*)d_in[2];
  const float* Wk = (const float*)d_in[3];
  const float* bk = (const float*)d_in[4];
  const float* Wv = (const float*)d_in[5];
  const float* bv = (const float*)d_in[6];
  const float* Wp = (const float*)d_in[7];
  const float* bp = (const float*)d_in[8];
  float* out = (float*)d_out;

  const int M = 8192, C = 1024;           // B*T, channels
  const size_t MC = (size_t)M * C, CC = (size_t)C * C;
  const size_t need = (MC * 5 + CC * 4) * sizeof(ushort);   // ~88 MB
  if (ws_size < need) return;             // loud failure instead of corruption

  ushort* xb  = (ushort*)d_ws;
  ushort* wqb = xb + MC;
  ushort* wkb = wqb + CC;
  ushort* wvb = wkb + CC;
  ushort* wpb = wvb + CC;
  ushort* Qb  = wpb + CC;
  ushort* Kb  = Qb + MC;
  ushort* Vb  = Kb + MC;
  ushort* Yb  = Vb + MC;

  f2bf_kernel<<<2048, 256, 0, stream>>>(x,  xb,  (int)(MC / 4));
  f2bf_kernel<<<512,  256, 0, stream>>>(Wq, wqb, (int)(CC / 4));
  f2bf_kernel<<<512,  256, 0, stream>>>(Wk, wkb, (int)(CC / 4));
  f2bf_kernel<<<512,  256, 0, stream>>>(Wv, wvb, (int)(CC / 4));
  f2bf_kernel<<<512,  256, 0, stream>>>(Wp, wpb, (int)(CC / 4));

  dim3 gg(8, 64);  // N/128, M/128
  gemm_bt<<<gg, 256, 0, stream>>>(xb, wqb, bq, nullptr, Qb, M, C, C);
  gemm_bt<<<gg, 256, 0, stream>>>(xb, wkb, bk, nullptr, Kb, M, C, C);
  gemm_bt<<<gg, 256, 0, stream>>>(xb, wvb, bv, nullptr, Vb, M, C, C);

  attn_kernel<<<dim3(32, 64), 256, 0, stream>>>(Qb, Kb, Vb, Yb);

  gemm_bt<<<gg, 256, 0, stream>>>(Yb, wpb, bp, out, nullptr, M, C, C);
}

// Round 3
// 301.167 us; speedup vs baseline: 1.3207x; 1.3207x over previous
//
#include <hip/hip_runtime.h>
#include <hip/hip_bf16.h>

typedef float  f32x4  __attribute__((ext_vector_type(4)));
typedef short  bf16x8 __attribute__((ext_vector_type(8)));

__device__ __forceinline__ ushort f2b(float f) {
  union { float f; unsigned u; } x; x.f = f;
  unsigned r = x.u + 0x7fffu + ((x.u >> 16) & 1u);   // RNE
  return (ushort)(r >> 16);
}

__device__ __forceinline__ unsigned pk2(float lo, float hi) {
  __hip_bfloat162 t = __float22bfloat162_rn(make_float2(lo, hi));
  union { __hip_bfloat162 b; unsigned u; } c; c.b = t; return c.u;   // low half = lo
}

__device__ __forceinline__ f32x4 fzero() {
  f32x4 z; z[0] = 0.f; z[1] = 0.f; z[2] = 0.f; z[3] = 0.f; return z;
}

__device__ __forceinline__ void gld_lds16(const ushort* g, ushort* l) {
  __builtin_amdgcn_global_load_lds(g, l, 16, 0, 0);
}

// j (token-within-64-tile) -> stored slot s:  j=32kk+16h+4g+r -> s=32kk+8g+4h+r
__device__ __forceinline__ int vperm_s(int j64) {
  return (j64 & 0x23) | ((j64 & 0x0C) << 1) | ((j64 & 0x10) >> 2);
}

// ---------------- fp32 -> bf16 convert ----------------
__global__ __launch_bounds__(256) void f2bf_kernel(const float* __restrict__ in,
                                                   ushort* __restrict__ out, int n4) {
  int idx = blockIdx.x * 256 + threadIdx.x;
  int stride = gridDim.x * 256;
  for (int i = idx; i < n4; i += stride) {
    float4 v = reinterpret_cast<const float4*>(in)[i];
    ushort4 o;
    o.x = f2b(v.x); o.y = f2b(v.y); o.z = f2b(v.z); o.w = f2b(v.w);
    reinterpret_cast<ushort4*>(out)[i] = o;
  }
}

// 4 weight matrices in one launch (blockIdx.y selects), outputs contiguous
__global__ __launch_bounds__(256) void f2bf_w4(
    const float* __restrict__ w0, const float* __restrict__ w1,
    const float* __restrict__ w2, const float* __restrict__ w3,
    ushort* __restrict__ out, int n4) {
  const float* src = (blockIdx.y == 0) ? w0 : (blockIdx.y == 1) ? w1
                   : (blockIdx.y == 2) ? w2 : w3;
  ushort* dst = out + (size_t)blockIdx.y * (size_t)n4 * 4;
  int idx = blockIdx.x * 256 + threadIdx.x;
  int stride = gridDim.x * 256;
  for (int i = idx; i < n4; i += stride) {
    float4 v = reinterpret_cast<const float4*>(src)[i];
    ushort4 o;
    o.x = f2b(v.x); o.y = f2b(v.y); o.z = f2b(v.z); o.w = f2b(v.w);
    reinterpret_cast<ushort4*>(dst)[i] = o;
  }
}

// ---------------- C[i,j] = (sum_k A[i,k]*B[j,k] + bias[j]) * scale ----------------
// m97 structure: 128x128 tile, BK=32, 4 waves. Verified R0.
__global__ __launch_bounds__(256) void gemm_bt(
    const ushort* __restrict__ A,    // [M,K] bf16
    const ushort* __restrict__ B,    // [N,K] bf16
    const float*  __restrict__ bias, // [N]
    float*  __restrict__ Cf,         // fp32 out (or null)
    ushort* __restrict__ Cb,         // bf16 out (or null)
    int M, int N, int K, float scale) {
  __shared__ ushort As[128 * 32];
  __shared__ ushort Bs[128 * 32];
  const int tid  = threadIdx.x;
  const int lane = tid & 63;
  const int wave = tid >> 6;
  const int wr = (wave >> 1) << 6;
  const int wc = (wave & 1) << 6;
  const int fr  = lane & 15;
  const int fk8 = (lane >> 4) << 3;

  const size_t rowA = (size_t)blockIdx.y * 128;
  const size_t rowB = (size_t)blockIdx.x * 128;
  const ushort* Ag = A + rowA * K;
  const ushort* Bg = B + rowB * K;

  const int c0 = tid, c1 = tid + 256;
  const size_t a0 = (size_t)(c0 >> 2) * K + (size_t)((c0 & 3) << 3);
  const size_t a1 = (size_t)(c1 >> 2) * K + (size_t)((c1 & 3) << 3);

  f32x4 acc[4][4];
#pragma unroll
  for (int m = 0; m < 4; ++m)
#pragma unroll
    for (int n = 0; n < 4; ++n) acc[m][n] = fzero();

  for (int k0 = 0; k0 < K; k0 += 32) {
    __syncthreads();
    gld_lds16(Ag + a0 + k0, &As[wave * 512]);
    gld_lds16(Ag + a1 + k0, &As[2048 + wave * 512]);
    gld_lds16(Bg + a0 + k0, &Bs[wave * 512]);
    gld_lds16(Bg + a1 + k0, &Bs[2048 + wave * 512]);
    asm volatile("s_waitcnt vmcnt(0)" ::: "memory");
    __syncthreads();

    bf16x8 af[4], bfv[4];
#pragma unroll
    for (int m = 0; m < 4; ++m)
      af[m] = *reinterpret_cast<const bf16x8*>(&As[(wr + m * 16 + fr) * 32 + fk8]);
#pragma unroll
    for (int n = 0; n < 4; ++n)
      bfv[n] = *reinterpret_cast<const bf16x8*>(&Bs[(wc + n * 16 + fr) * 32 + fk8]);
#pragma unroll
    for (int m = 0; m < 4; ++m)
#pragma unroll
      for (int n = 0; n < 4; ++n)
        acc[m][n] = __builtin_amdgcn_mfma_f32_16x16x32_bf16(af[m], bfv[n], acc[m][n], 0, 0, 0);
  }

  const int orow = (lane >> 4) << 2;
#pragma unroll
  for (int m = 0; m < 4; ++m) {
#pragma unroll
    for (int n = 0; n < 4; ++n) {
      size_t gc = rowB + wc + n * 16 + fr;
      float bv = bias[gc];
#pragma unroll
      for (int r = 0; r < 4; ++r) {
        size_t gr = rowA + wr + m * 16 + orow + r;
        float v = (acc[m][n][r] + bv) * scale;
        if (Cf) Cf[gr * N + gc] = v;
        else    Cb[gr * N + gc] = f2b(v);
      }
    }
  }
}

// ---------------- V projection: same GEMM core, writes V^T j-permuted ----------------
// Out layout: VbT[b][c][ (t & ~63) + vperm_s(t & 63) ]  (b = token>>11, t = token&2047)
__global__ __launch_bounds__(256) void gemm_bt_vt(
    const ushort* __restrict__ A,    // [8192,1024] bf16 (x)
    const ushort* __restrict__ B,    // [1024,1024] bf16 (Wv)
    const float*  __restrict__ bias,
    ushort* __restrict__ VbT,
    int M, int N, int K) {
  __shared__ ushort As[128 * 32];
  __shared__ ushort Bs[128 * 32];
  const int tid  = threadIdx.x;
  const int lane = tid & 63;
  const int wave = tid >> 6;
  const int wr = (wave >> 1) << 6;
  const int wc = (wave & 1) << 6;
  const int fr  = lane & 15;
  const int fk8 = (lane >> 4) << 3;

  const size_t rowA = (size_t)blockIdx.y * 128;
  const size_t rowB = (size_t)blockIdx.x * 128;
  const ushort* Ag = A + rowA * K;
  const ushort* Bg = B + rowB * K;

  const int c0 = tid, c1 = tid + 256;
  const size_t a0 = (size_t)(c0 >> 2) * K + (size_t)((c0 & 3) << 3);
  const size_t a1 = (size_t)(c1 >> 2) * K + (size_t)((c1 & 3) << 3);

  f32x4 acc[4][4];
#pragma unroll
  for (int m = 0; m < 4; ++m)
#pragma unroll
    for (int n = 0; n < 4; ++n) acc[m][n] = fzero();

  for (int k0 = 0; k0 < K; k0 += 32) {
    __syncthreads();
    gld_lds16(Ag + a0 + k0, &As[wave * 512]);
    gld_lds16(Ag + a1 + k0, &As[2048 + wave * 512]);
    gld_lds16(Bg + a0 + k0, &Bs[wave * 512]);
    gld_lds16(Bg + a1 + k0, &Bs[2048 + wave * 512]);
    asm volatile("s_waitcnt vmcnt(0)" ::: "memory");
    __syncthreads();

    bf16x8 af[4], bfv[4];
#pragma unroll
    for (int m = 0; m < 4; ++m)
      af[m] = *reinterpret_cast<const bf16x8*>(&As[(wr + m * 16 + fr) * 32 + fk8]);
#pragma unroll
    for (int n = 0; n < 4; ++n)
      bfv[n] = *reinterpret_cast<const bf16x8*>(&Bs[(wc + n * 16 + fr) * 32 + fk8]);
#pragma unroll
    for (int m = 0; m < 4; ++m)
#pragma unroll
      for (int n = 0; n < 4; ++n)
        acc[m][n] = __builtin_amdgcn_mfma_f32_16x16x32_bf16(af[m], bfv[n], acc[m][n], 0, 0, 0);
  }

  const int orow = (lane >> 4) << 2;
#pragma unroll
  for (int m = 0; m < 4; ++m) {
#pragma unroll
    for (int n = 0; n < 4; ++n) {
      size_t gc = rowB + wc + n * 16 + fr;   // channel
      float bv = bias[gc];
#pragma unroll
      for (int r = 0; r < 4; ++r) {
        int tt = (int)rowA + wr + m * 16 + orow + r;   // token
        int b = tt >> 11, t = tt & 2047;
        size_t idx = (size_t)b * 2097152 + gc * 2048 + (size_t)((t & ~63) + vperm_s(t & 63));
        VbT[idx] = f2b(acc[m][n][r] + bv);
      }
    }
  }
}

// ---------------- flash attention: swapped QK^T, in-lane softmax/P, V^T from global ----------------
// grid (32 qtiles, 64 b*h), 4 waves; wave owns 16 q-rows (q-row = lane&15), KV tile = 64.
// Q pre-scaled by 0.125*log2(e) -> softmax in exp2 domain.
// PV computed as Y^T = V^T * P^T: output col = lane's own q-row -> no shuffles for alpha/l.
__global__ __launch_bounds__(256) void attn_kernel(
    const ushort* __restrict__ Qb, const ushort* __restrict__ Kb,
    const ushort* __restrict__ VbT, ushort* __restrict__ Yb) {
  __shared__ ushort Ks[2][4096];   // [64 j][8 chunk][8], chunk pos w holds d-chunk (w ^ (j&7))
  __shared__ ushort Vs[2][4096];   // [64 d][8 chunk][8], chunk pos w holds s-chunk (w ^ (d&7))
  const int tid = threadIdx.x, lane = tid & 63, wave = tid >> 6;
  const int fr = lane & 15, g = lane >> 4, fk8 = g << 3;
  const int bb = blockIdx.y >> 4, h = blockIdx.y & 15;
  const size_t rowbase = (size_t)bb * 2048;
  const int cbase = h * 64;
  const ushort* Kg  = Kb  + rowbase * 1024 + cbase;
  const ushort* VgT = VbT + (size_t)bb * 2097152 + (size_t)cbase * 2048;

  // Q B-fragment: lane holds q-row i = fr, k-slots d = kk*32 + 8g + 0..7
  const int qrow = blockIdx.x * 64 + wave * 16 + fr;
  const ushort* qptr = &Qb[(rowbase + qrow) * 1024 + cbase];
  const bf16x8 qf0 = *reinterpret_cast<const bf16x8*>(qptr + fk8);
  const bf16x8 qf1 = *reinterpret_cast<const bf16x8*>(qptr + 32 + fk8);

  // staging: 512 chunks x 16B per tile, 2 per thread; chunk c -> LDS elems 8c..8c+7
  const int c0 = tid, c1 = tid + 256;
  const int r0 = c0 >> 3, r1 = c1 >> 3;           // K row / V^T d-row within tile
  const int w0 = (c0 & 7) ^ (r0 & 7), w1 = (c1 & 7) ^ (r1 & 7);
  const ushort* sK0 = Kg + (size_t)r0 * 1024 + (w0 << 3);
  const ushort* sK1 = Kg + (size_t)r1 * 1024 + (w1 << 3);
  const ushort* sV0 = VgT + (size_t)r0 * 2048 + (w0 << 3);
  const ushort* sV1 = VgT + (size_t)r1 * 2048 + (w1 << 3);

  f32x4 yacc[4];
#pragma unroll
  for (int nb = 0; nb < 4; ++nb) yacc[nb] = fzero();
  float mrow = -__builtin_inff(), lrow = 0.f;

  // prologue: stage tile 0 into buf 0
  gld_lds16(sK0, &Ks[0][wave * 512]);
  gld_lds16(sK1, &Ks[0][2048 + wave * 512]);
  gld_lds16(sV0, &Vs[0][wave * 512]);
  gld_lds16(sV1, &Vs[0][2048 + wave * 512]);
  asm volatile("s_waitcnt vmcnt(0)" ::: "memory");
  __syncthreads();

  for (int t = 0; t < 32; ++t) {
    const int cur = t & 1;
    if (t < 31) {   // prefetch next tile into other buffer (safe: all waves passed barrier)
      const size_t offK = (size_t)(t + 1) * 65536;   // 64 rows * 1024
      const int    offV = (t + 1) * 64;              // 64 cols in [d][2048] layout
      gld_lds16(sK0 + offK, &Ks[cur ^ 1][wave * 512]);
      gld_lds16(sK1 + offK, &Ks[cur ^ 1][2048 + wave * 512]);
      gld_lds16(sV0 + offV, &Vs[cur ^ 1][wave * 512]);
      gld_lds16(sV1 + offV, &Vs[cur ^ 1][2048 + wave * 512]);
    }

    // S^T = K Q^T: sT[jb] reg r = S[j = 16jb + 4g + r][i = fr]
    f32x4 sT[4];
#pragma unroll
    for (int jb = 0; jb < 4; ++jb) {
      const int krow = jb * 16 + fr;
      const int sw = (krow & 7) << 3;
      bf16x8 kf0 = *reinterpret_cast<const bf16x8*>(&Ks[cur][krow * 64 + (fk8 ^ sw)]);
      bf16x8 kf1 = *reinterpret_cast<const bf16x8*>(&Ks[cur][krow * 64 + ((32 + fk8) ^ sw)]);
      f32x4 z = fzero();
      __builtin_amdgcn_s_setprio(1);
      z = __builtin_amdgcn_mfma_f32_16x16x32_bf16(kf0, qf0, z, 0, 0, 0);
      z = __builtin_amdgcn_mfma_f32_16x16x32_bf16(kf1, qf1, z, 0, 0, 0);
      __builtin_amdgcn_s_setprio(0);
      sT[jb] = z;
    }

    // online softmax: lane owns q-row fr; partners are lanes {fr, fr+16, fr+32, fr+48}
    float mx = sT[0][0];
#pragma unroll
    for (int jb = 0; jb < 4; ++jb)
#pragma unroll
      for (int r = 0; r < 4; ++r) mx = fmaxf(mx, sT[jb][r]);
    mx = fmaxf(mx, __shfl_xor(mx, 16));
    mx = fmaxf(mx, __shfl_xor(mx, 32));
    const float mnew  = fmaxf(mrow, mx);
    const float alpha = __builtin_exp2f(mrow - mnew);
    float p[4][4];
    float psum = 0.f;
#pragma unroll
    for (int jb = 0; jb < 4; ++jb)
#pragma unroll
      for (int r = 0; r < 4; ++r) {
        p[jb][r] = __builtin_exp2f(sT[jb][r] - mnew);
        psum += p[jb][r];
      }
    psum += __shfl_xor(psum, 16);
    psum += __shfl_xor(psum, 32);
    lrow = lrow * alpha + psum;
    mrow = mnew;

    // P -> bf16 B-fragments, in-lane: k-slot 8g+f <-> j = 32kk + 16(f>>2) + 4g + (f&3)
    union { bf16x8 v; unsigned u[4]; } pa0, pa1;
    pa0.u[0] = pk2(p[0][0], p[0][1]); pa0.u[1] = pk2(p[0][2], p[0][3]);
    pa0.u[2] = pk2(p[1][0], p[1][1]); pa0.u[3] = pk2(p[1][2], p[1][3]);
    pa1.u[0] = pk2(p[2][0], p[2][1]); pa1.u[1] = pk2(p[2][2], p[2][3]);
    pa1.u[2] = pk2(p[3][0], p[3][1]); pa1.u[3] = pk2(p[3][2], p[3][3]);

    // rescale: every yacc element belongs to q-row fr -> lane's own alpha
#pragma unroll
    for (int nb = 0; nb < 4; ++nb)
#pragma unroll
      for (int r = 0; r < 4; ++r) yacc[nb][r] *= alpha;

    // Y^T += V^T P^T: A-frag from Vs (slot s = 32kk+8g+f at chunk (4kk+g)^(d&7))
    const int dsw = fr & 7;
#pragma unroll
    for (int nb = 0; nb < 4; ++nb) {
      const int dd = (nb * 16 + fr) * 64;
      bf16x8 vf0 = *reinterpret_cast<const bf16x8*>(&Vs[cur][dd + ((g ^ dsw) << 3)]);
      bf16x8 vf1 = *reinterpret_cast<const bf16x8*>(&Vs[cur][dd + (((4 + g) ^ dsw) << 3)]);
      __builtin_amdgcn_s_setprio(1);
      yacc[nb] = __builtin_amdgcn_mfma_f32_16x16x32_bf16(vf0, pa0.v, yacc[nb], 0, 0, 0);
      yacc[nb] = __builtin_amdgcn_mfma_f32_16x16x32_bf16(vf1, pa1.v, yacc[nb], 0, 0, 0);
      __builtin_amdgcn_s_setprio(0);
    }

    asm volatile("s_waitcnt vmcnt(0)" ::: "memory");
    __syncthreads();
  }

  // epilogue: yacc[nb] reg r = Y[row qrow][d = 16nb + 4g + r]; lane's own 1/l
  const float linv = 1.0f / lrow;
  ushort* yrow = &Yb[(rowbase + qrow) * 1024 + cbase];
#pragma unroll
  for (int nb = 0; nb < 4; ++nb) {
    ushort4 o;
    o.x = f2b(yacc[nb][0] * linv);
    o.y = f2b(yacc[nb][1] * linv);
    o.z = f2b(yacc[nb][2] * linv);
    o.w = f2b(yacc[nb][3] * linv);
    *reinterpret_cast<ushort4*>(yrow + nb * 16 + (g << 2)) = o;
  }
}

extern "C" void kernel_launch(void* const* d_in, const int* in_sizes, int n_in,
                              void* d_out, int out_size, void* d_ws, size_t ws_size,
                              hipStream_t stream) {
  const float* x  = (const float*)d_in[0];
  const float* Wq = (const float*)d_in[1];
  const float* bq = (const float*)d_in[2];
  const float* Wk = (const float*)d_in[3];
  const float* bk = (const float*)d_in[4];
  const float* Wv = (const float*)d_in[5];
  const float* bv = (const float*)d_in[6];
  const float* Wp = (const float*)d_in[7];
  const float* bp = (const float*)d_in[8];
  float* out = (float*)d_out;

  const int M = 8192, C = 1024;
  const size_t MC = (size_t)M * C, CC = (size_t)C * C;
  const size_t need = (MC * 5 + CC * 4) * sizeof(ushort);
  if (ws_size < need) return;

  ushort* xb  = (ushort*)d_ws;
  ushort* wqb = xb + MC;     // wq,wk,wv,wp contiguous
  ushort* wkb = wqb + CC;
  ushort* wvb = wkb + CC;
  ushort* wpb = wvb + CC;
  ushort* Qb  = wpb + CC;
  ushort* Kb  = Qb + MC;
  ushort* VbT = Kb + MC;     // [4][1024][2048] transposed, j-permuted
  ushort* Yb  = VbT + MC;

  f2bf_kernel<<<2048, 256, 0, stream>>>(x, xb, (int)(MC / 4));
  f2bf_w4<<<dim3(256, 4), 256, 0, stream>>>(Wq, Wk, Wv, Wp, wqb, (int)(CC / 4));

  const float QSCALE = 0.18033688011112042f;  // 0.125 * log2(e): softmax in exp2 domain
  dim3 gg(8, 64);
  gemm_bt<<<gg, 256, 0, stream>>>(xb, wqb, bq, nullptr, Qb, M, C, C, QSCALE);
  gemm_bt<<<gg, 256, 0, stream>>>(xb, wkb, bk, nullptr, Kb, M, C, C, 1.0f);
  gemm_bt_vt<<<gg, 256, 0, stream>>>(xb, wvb, bv, VbT, M, C, C);

  attn_kernel<<<dim3(32, 64), 256, 0, stream>>>(Qb, Kb, VbT, Yb);

  gemm_bt<<<gg, 256, 0, stream>>>(Yb, wpb, bp, out, nullptr, M, C, C, 1.0f);
}

// Round 4
// 276.603 us; speedup vs baseline: 1.4380x; 1.0888x over previous
//
#include <hip/hip_runtime.h>
#include <hip/hip_bf16.h>

typedef float  f32x4  __attribute__((ext_vector_type(4)));
typedef short  bf16x8 __attribute__((ext_vector_type(8)));

__device__ __forceinline__ ushort f2b(float f) {
  union { float f; unsigned u; } x; x.f = f;
  unsigned r = x.u + 0x7fffu + ((x.u >> 16) & 1u);   // RNE
  return (ushort)(r >> 16);
}

__device__ __forceinline__ unsigned pk2(float lo, float hi) {
  __hip_bfloat162 t = __float22bfloat162_rn(make_float2(lo, hi));
  union { __hip_bfloat162 b; unsigned u; } c; c.b = t; return c.u;   // low half = lo
}

__device__ __forceinline__ f32x4 fzero() {
  f32x4 z; z[0] = 0.f; z[1] = 0.f; z[2] = 0.f; z[3] = 0.f; return z;
}

__device__ __forceinline__ void gld_lds16(const ushort* g, ushort* l) {
  __builtin_amdgcn_global_load_lds(g, l, 16, 0, 0);
}

// j (token-within-64-tile) -> stored slot s:  j=32kk+16h+4g+r -> s=32kk+8g+4h+r
__device__ __forceinline__ int vperm_s(int j64) {
  return (j64 & 0x23) | ((j64 & 0x0C) << 1) | ((j64 & 0x10) >> 2);
}

// ---------------- fp32 -> bf16 convert ----------------
__global__ __launch_bounds__(256) void f2bf_kernel(const float* __restrict__ in,
                                                   ushort* __restrict__ out, int n4) {
  int idx = blockIdx.x * 256 + threadIdx.x;
  int stride = gridDim.x * 256;
  for (int i = idx; i < n4; i += stride) {
    float4 v = reinterpret_cast<const float4*>(in)[i];
    ushort4 o;
    o.x = f2b(v.x); o.y = f2b(v.y); o.z = f2b(v.z); o.w = f2b(v.w);
    reinterpret_cast<ushort4*>(out)[i] = o;
  }
}

// 4 weight matrices in one launch (blockIdx.y selects), outputs contiguous
__global__ __launch_bounds__(256) void f2bf_w4(
    const float* __restrict__ w0, const float* __restrict__ w1,
    const float* __restrict__ w2, const float* __restrict__ w3,
    ushort* __restrict__ out, int n4) {
  const float* src = (blockIdx.y == 0) ? w0 : (blockIdx.y == 1) ? w1
                   : (blockIdx.y == 2) ? w2 : w3;
  ushort* dst = out + (size_t)blockIdx.y * (size_t)n4 * 4;
  int idx = blockIdx.x * 256 + threadIdx.x;
  int stride = gridDim.x * 256;
  for (int i = idx; i < n4; i += stride) {
    float4 v = reinterpret_cast<const float4*>(src)[i];
    ushort4 o;
    o.x = f2b(v.x); o.y = f2b(v.y); o.z = f2b(v.z); o.w = f2b(v.w);
    reinterpret_cast<ushort4*>(dst)[i] = o;
  }
}

// ---------------- C[i,j] = (sum_k A[i,k]*B[j,k] + bias[j]) * scale ----------------
// m97 structure: 128x128 tile, BK=32, 4 waves. Verified R0.
__global__ __launch_bounds__(256) void gemm_bt(
    const ushort* __restrict__ A,    // [M,K] bf16
    const ushort* __restrict__ B,    // [N,K] bf16
    const float*  __restrict__ bias, // [N]
    float*  __restrict__ Cf,         // fp32 out (or null)
    ushort* __restrict__ Cb,         // bf16 out (or null)
    int M, int N, int K, float scale) {
  __shared__ ushort As[128 * 32];
  __shared__ ushort Bs[128 * 32];
  const int tid  = threadIdx.x;
  const int lane = tid & 63;
  const int wave = tid >> 6;
  const int wr = (wave >> 1) << 6;
  const int wc = (wave & 1) << 6;
  const int fr  = lane & 15;
  const int fk8 = (lane >> 4) << 3;

  const size_t rowA = (size_t)blockIdx.y * 128;
  const size_t rowB = (size_t)blockIdx.x * 128;
  const ushort* Ag = A + rowA * K;
  const ushort* Bg = B + rowB * K;

  const int c0 = tid, c1 = tid + 256;
  const size_t a0 = (size_t)(c0 >> 2) * K + (size_t)((c0 & 3) << 3);
  const size_t a1 = (size_t)(c1 >> 2) * K + (size_t)((c1 & 3) << 3);

  f32x4 acc[4][4];
#pragma unroll
  for (int m = 0; m < 4; ++m)
#pragma unroll
    for (int n = 0; n < 4; ++n) acc[m][n] = fzero();

  for (int k0 = 0; k0 < K; k0 += 32) {
    __syncthreads();
    gld_lds16(Ag + a0 + k0, &As[wave * 512]);
    gld_lds16(Ag + a1 + k0, &As[2048 + wave * 512]);
    gld_lds16(Bg + a0 + k0, &Bs[wave * 512]);
    gld_lds16(Bg + a1 + k0, &Bs[2048 + wave * 512]);
    asm volatile("s_waitcnt vmcnt(0)" ::: "memory");
    __syncthreads();

    bf16x8 af[4], bfv[4];
#pragma unroll
    for (int m = 0; m < 4; ++m)
      af[m] = *reinterpret_cast<const bf16x8*>(&As[(wr + m * 16 + fr) * 32 + fk8]);
#pragma unroll
    for (int n = 0; n < 4; ++n)
      bfv[n] = *reinterpret_cast<const bf16x8*>(&Bs[(wc + n * 16 + fr) * 32 + fk8]);
#pragma unroll
    for (int m = 0; m < 4; ++m)
#pragma unroll
      for (int n = 0; n < 4; ++n)
        acc[m][n] = __builtin_amdgcn_mfma_f32_16x16x32_bf16(af[m], bfv[n], acc[m][n], 0, 0, 0);
  }

  const int orow = (lane >> 4) << 2;
#pragma unroll
  for (int m = 0; m < 4; ++m) {
#pragma unroll
    for (int n = 0; n < 4; ++n) {
      size_t gc = rowB + wc + n * 16 + fr;
      float bv = bias[gc];
#pragma unroll
      for (int r = 0; r < 4; ++r) {
        size_t gr = rowA + wr + m * 16 + orow + r;
        float v = (acc[m][n][r] + bv) * scale;
        if (Cf) Cf[gr * N + gc] = v;
        else    Cb[gr * N + gc] = f2b(v);
      }
    }
  }
}

// ---------------- V projection: same GEMM core, writes V^T j-permuted ----------------
// Out layout: VbT[b][c][ (t & ~63) + vperm_s(t & 63) ]  (b = token>>11, t = token&2047)
__global__ __launch_bounds__(256) void gemm_bt_vt(
    const ushort* __restrict__ A,    // [8192,1024] bf16 (x)
    const ushort* __restrict__ B,    // [1024,1024] bf16 (Wv)
    const float*  __restrict__ bias,
    ushort* __restrict__ VbT,
    int M, int N, int K) {
  __shared__ ushort As[128 * 32];
  __shared__ ushort Bs[128 * 32];
  const int tid  = threadIdx.x;
  const int lane = tid & 63;
  const int wave = tid >> 6;
  const int wr = (wave >> 1) << 6;
  const int wc = (wave & 1) << 6;
  const int fr  = lane & 15;
  const int fk8 = (lane >> 4) << 3;

  const size_t rowA = (size_t)blockIdx.y * 128;
  const size_t rowB = (size_t)blockIdx.x * 128;
  const ushort* Ag = A + rowA * K;
  const ushort* Bg = B + rowB * K;

  const int c0 = tid, c1 = tid + 256;
  const size_t a0 = (size_t)(c0 >> 2) * K + (size_t)((c0 & 3) << 3);
  const size_t a1 = (size_t)(c1 >> 2) * K + (size_t)((c1 & 3) << 3);

  f32x4 acc[4][4];
#pragma unroll
  for (int m = 0; m < 4; ++m)
#pragma unroll
    for (int n = 0; n < 4; ++n) acc[m][n] = fzero();

  for (int k0 = 0; k0 < K; k0 += 32) {
    __syncthreads();
    gld_lds16(Ag + a0 + k0, &As[wave * 512]);
    gld_lds16(Ag + a1 + k0, &As[2048 + wave * 512]);
    gld_lds16(Bg + a0 + k0, &Bs[wave * 512]);
    gld_lds16(Bg + a1 + k0, &Bs[2048 + wave * 512]);
    asm volatile("s_waitcnt vmcnt(0)" ::: "memory");
    __syncthreads();

    bf16x8 af[4], bfv[4];
#pragma unroll
    for (int m = 0; m < 4; ++m)
      af[m] = *reinterpret_cast<const bf16x8*>(&As[(wr + m * 16 + fr) * 32 + fk8]);
#pragma unroll
    for (int n = 0; n < 4; ++n)
      bfv[n] = *reinterpret_cast<const bf16x8*>(&Bs[(wc + n * 16 + fr) * 32 + fk8]);
#pragma unroll
    for (int m = 0; m < 4; ++m)
#pragma unroll
      for (int n = 0; n < 4; ++n)
        acc[m][n] = __builtin_amdgcn_mfma_f32_16x16x32_bf16(af[m], bfv[n], acc[m][n], 0, 0, 0);
  }

  const int orow = (lane >> 4) << 2;
#pragma unroll
  for (int m = 0; m < 4; ++m) {
#pragma unroll
    for (int n = 0; n < 4; ++n) {
      size_t gc = rowB + wc + n * 16 + fr;   // channel
      float bv = bias[gc];
#pragma unroll
      for (int r = 0; r < 4; ++r) {
        int tt = (int)rowA + wr + m * 16 + orow + r;   // token
        int b = tt >> 11, t = tt & 2047;
        size_t idx = (size_t)b * 2097152 + gc * 2048 + (size_t)((t & ~63) + vperm_s(t & 63));
        VbT[idx] = f2b(acc[m][n][r] + bv);
      }
    }
  }
}

// ---------------- flash attention: 8 waves, QBLK=128, swapped QK^T, in-lane softmax ----------------
// grid (16 qtiles, 64 b*h), 8 waves; wave owns 16 q-rows (q-row = lane&15), KV tile = 64.
// Q pre-scaled by 0.125*log2(e) -> softmax in exp2 domain; defer-max THR=8.
__global__ __launch_bounds__(512) void attn_kernel(
    const ushort* __restrict__ Qb, const ushort* __restrict__ Kb,
    const ushort* __restrict__ VbT, ushort* __restrict__ Yb) {
  __shared__ ushort Ks[2][4096];   // [64 j][8 chunk][8], chunk pos w holds d-chunk (w ^ (j&7))
  __shared__ ushort Vs[2][4096];   // [64 d][8 chunk][8], chunk pos w holds s-chunk (w ^ (d&7))
  const int tid = threadIdx.x, lane = tid & 63, wave = tid >> 6;
  const int fr = lane & 15, g = lane >> 4, fk8 = g << 3;
  const int bb = blockIdx.y >> 4, h = blockIdx.y & 15;
  const size_t rowbase = (size_t)bb * 2048;
  const int cbase = h * 64;
  const ushort* Kg  = Kb  + rowbase * 1024 + cbase;
  const ushort* VgT = VbT + (size_t)bb * 2097152 + (size_t)cbase * 2048;

  // Q B-fragment: lane holds q-row i = fr, k-slots d = kk*32 + 8g + 0..7
  const int qrow = blockIdx.x * 128 + wave * 16 + fr;
  const ushort* qptr = &Qb[(rowbase + qrow) * 1024 + cbase];
  const bf16x8 qf0 = *reinterpret_cast<const bf16x8*>(qptr + fk8);
  const bf16x8 qf1 = *reinterpret_cast<const bf16x8*>(qptr + 32 + fk8);

  // staging: 512 chunks x 16B per tile, 1 per thread; chunk c=tid -> LDS elems 8c..8c+7
  const int rS = tid >> 3;                         // row within tile (K j-row / V d-row)
  const int wS = (tid & 7) ^ (rS & 7);             // swizzled chunk position
  const ushort* sK = Kg  + (size_t)rS * 1024 + (wS << 3);
  const ushort* sV = VgT + (size_t)rS * 2048 + (wS << 3);

  f32x4 yacc[4];
#pragma unroll
  for (int nb = 0; nb < 4; ++nb) yacc[nb] = fzero();
  float mrow = -__builtin_inff(), lrow = 0.f;

  // prologue: stage tile 0 into buf 0 (each wave stages its 64 chunks)
  gld_lds16(sK, &Ks[0][wave * 512]);
  gld_lds16(sV, &Vs[0][wave * 512]);
  asm volatile("s_waitcnt vmcnt(0)" ::: "memory");
  __syncthreads();

  for (int t = 0; t < 32; ++t) {
    const int cur = t & 1;
    if (t < 31) {   // prefetch next tile into other buffer (safe: all waves passed barrier)
      gld_lds16(sK + (size_t)(t + 1) * 65536, &Ks[cur ^ 1][wave * 512]);
      gld_lds16(sV + (t + 1) * 64,            &Vs[cur ^ 1][wave * 512]);
    }

    // S^T = K Q^T: sT[jb] reg r = S[j = 16jb + 4g + r][i = fr]
    f32x4 sT[4];
#pragma unroll
    for (int jb = 0; jb < 4; ++jb) {
      const int krow = jb * 16 + fr;
      const int sw = (krow & 7) << 3;
      bf16x8 kf0 = *reinterpret_cast<const bf16x8*>(&Ks[cur][krow * 64 + (fk8 ^ sw)]);
      bf16x8 kf1 = *reinterpret_cast<const bf16x8*>(&Ks[cur][krow * 64 + ((32 + fk8) ^ sw)]);
      f32x4 z = fzero();
      __builtin_amdgcn_s_setprio(1);
      z = __builtin_amdgcn_mfma_f32_16x16x32_bf16(kf0, qf0, z, 0, 0, 0);
      z = __builtin_amdgcn_mfma_f32_16x16x32_bf16(kf1, qf1, z, 0, 0, 0);
      __builtin_amdgcn_s_setprio(0);
      sT[jb] = z;
    }

    // online softmax: lane owns q-row fr; partners are lanes {fr, fr+16, fr+32, fr+48}
    float mx = sT[0][0];
#pragma unroll
    for (int jb = 0; jb < 4; ++jb)
#pragma unroll
      for (int r = 0; r < 4; ++r) mx = fmaxf(mx, sT[jb][r]);
    mx = fmaxf(mx, __shfl_xor(mx, 16));
    mx = fmaxf(mx, __shfl_xor(mx, 32));

    // defer-max (T13): skip rescale when max growth <= 8 (P bounded by 2^8)
    if (!__all(mx <= mrow + 8.0f)) {
      const float mnew  = fmaxf(mrow, mx);
      const float alpha = __builtin_exp2f(mrow - mnew);
      lrow *= alpha;
#pragma unroll
      for (int nb = 0; nb < 4; ++nb)
#pragma unroll
        for (int r = 0; r < 4; ++r) yacc[nb][r] *= alpha;
      mrow = mnew;
    }

    float p[4][4];
    float psum = 0.f;
#pragma unroll
    for (int jb = 0; jb < 4; ++jb)
#pragma unroll
      for (int r = 0; r < 4; ++r) {
        p[jb][r] = __builtin_exp2f(sT[jb][r] - mrow);
        psum += p[jb][r];
      }
    psum += __shfl_xor(psum, 16);
    psum += __shfl_xor(psum, 32);
    lrow += psum;

    // P -> bf16 B-fragments, in-lane: k-slot 8g+f <-> j = 32kk + 16(f>>2) + 4g + (f&3)
    union { bf16x8 v; unsigned u[4]; } pa0, pa1;
    pa0.u[0] = pk2(p[0][0], p[0][1]); pa0.u[1] = pk2(p[0][2], p[0][3]);
    pa0.u[2] = pk2(p[1][0], p[1][1]); pa0.u[3] = pk2(p[1][2], p[1][3]);
    pa1.u[0] = pk2(p[2][0], p[2][1]); pa1.u[1] = pk2(p[2][2], p[2][3]);
    pa1.u[2] = pk2(p[3][0], p[3][1]); pa1.u[3] = pk2(p[3][2], p[3][3]);

    // Y^T += V^T P^T: A-frag from Vs (slot s = 32kk+8g+f at chunk (4kk+g)^(d&7))
    const int dsw = fr & 7;
#pragma unroll
    for (int nb = 0; nb < 4; ++nb) {
      const int dd = (nb * 16 + fr) * 64;
      bf16x8 vf0 = *reinterpret_cast<const bf16x8*>(&Vs[cur][dd + ((g ^ dsw) << 3)]);
      bf16x8 vf1 = *reinterpret_cast<const bf16x8*>(&Vs[cur][dd + (((4 + g) ^ dsw) << 3)]);
      __builtin_amdgcn_s_setprio(1);
      yacc[nb] = __builtin_amdgcn_mfma_f32_16x16x32_bf16(vf0, pa0.v, yacc[nb], 0, 0, 0);
      yacc[nb] = __builtin_amdgcn_mfma_f32_16x16x32_bf16(vf1, pa1.v, yacc[nb], 0, 0, 0);
      __builtin_amdgcn_s_setprio(0);
    }

    asm volatile("s_waitcnt vmcnt(0)" ::: "memory");
    __syncthreads();
  }

  // epilogue: yacc[nb] reg r = Y[row qrow][d = 16nb + 4g + r]; lane's own 1/l
  const float linv = 1.0f / lrow;
  ushort* yrow = &Yb[(rowbase + qrow) * 1024 + cbase];
#pragma unroll
  for (int nb = 0; nb < 4; ++nb) {
    ushort4 o;
    o.x = f2b(yacc[nb][0] * linv);
    o.y = f2b(yacc[nb][1] * linv);
    o.z = f2b(yacc[nb][2] * linv);
    o.w = f2b(yacc[nb][3] * linv);
    *reinterpret_cast<ushort4*>(yrow + nb * 16 + (g << 2)) = o;
  }
}

extern "C" void kernel_launch(void* const* d_in, const int* in_sizes, int n_in,
                              void* d_out, int out_size, void* d_ws, size_t ws_size,
                              hipStream_t stream) {
  const float* x  = (const float*)d_in[0];
  const float* Wq = (const float*)d_in[1];
  const float* bq = (const float*)d_in[2];
  const float* Wk = (const float*)d_in[3];
  const float* bk = (const float*)d_in[4];
  const float* Wv = (const float*)d_in[5];
  const float* bv = (const float*)d_in[6];
  const float* Wp = (const float*)d_in[7];
  const float* bp = (const float*)d_in[8];
  float* out = (float*)d_out;

  const int M = 8192, C = 1024;
  const size_t MC = (size_t)M * C, CC = (size_t)C * C;
  const size_t need = (MC * 5 + CC * 4) * sizeof(ushort);
  if (ws_size < need) return;

  ushort* xb  = (ushort*)d_ws;
  ushort* wqb = xb + MC;     // wq,wk,wv,wp contiguous
  ushort* wkb = wqb + CC;
  ushort* wvb = wkb + CC;
  ushort* wpb = wvb + CC;
  ushort* Qb  = wpb + CC;
  ushort* Kb  = Qb + MC;
  ushort* VbT = Kb + MC;     // [4][1024][2048] transposed, j-permuted
  ushort* Yb  = VbT + MC;

  f2bf_kernel<<<2048, 256, 0, stream>>>(x, xb, (int)(MC / 4));
  f2bf_w4<<<dim3(256, 4), 256, 0, stream>>>(Wq, Wk, Wv, Wp, wqb, (int)(CC / 4));

  const float QSCALE = 0.18033688011112042f;  // 0.125 * log2(e): softmax in exp2 domain
  dim3 gg(8, 64);
  gemm_bt<<<gg, 256, 0, stream>>>(xb, wqb, bq, nullptr, Qb, M, C, C, QSCALE);
  gemm_bt<<<gg, 256, 0, stream>>>(xb, wkb, bk, nullptr, Kb, M, C, C, 1.0f);
  gemm_bt_vt<<<gg, 256, 0, stream>>>(xb, wvb, bv, VbT, M, C, C);

  attn_kernel<<<dim3(16, 64), 512, 0, stream>>>(Qb, Kb, VbT, Yb);

  gemm_bt<<<gg, 256, 0, stream>>>(Yb, wpb, bp, out, nullptr, M, C, C, 1.0f);
}

// Round 5
// 247.872 us; speedup vs baseline: 1.6047x; 1.1159x over previous
//
#include <hip/hip_runtime.h>
#include <hip/hip_bf16.h>

typedef float  f32x4  __attribute__((ext_vector_type(4)));
typedef short  bf16x8 __attribute__((ext_vector_type(8)));

__device__ __forceinline__ ushort f2b(float f) {
  union { float f; unsigned u; } x; x.f = f;
  unsigned r = x.u + 0x7fffu + ((x.u >> 16) & 1u);   // RNE
  return (ushort)(r >> 16);
}

__device__ __forceinline__ unsigned pk2(float lo, float hi) {
  __hip_bfloat162 t = __float22bfloat162_rn(make_float2(lo, hi));
  union { __hip_bfloat162 b; unsigned u; } c; c.b = t; return c.u;   // low half = lo
}

__device__ __forceinline__ f32x4 fzero() {
  f32x4 z; z[0] = 0.f; z[1] = 0.f; z[2] = 0.f; z[3] = 0.f; return z;
}

__device__ __forceinline__ void gld_lds16(const ushort* g, ushort* l) {
  __builtin_amdgcn_global_load_lds(g, l, 16, 0, 0);
}

// j (token-within-64-tile) -> stored slot s:  j=32kk+16h+4g+r -> s=32kk+8g+4h+r
__device__ __forceinline__ int vperm_s(int j64) {
  return (j64 & 0x23) | ((j64 & 0x0C) << 1) | ((j64 & 0x10) >> 2);
}

// ---------------- fp32 -> bf16 convert ----------------
__global__ __launch_bounds__(256) void f2bf_kernel(const float* __restrict__ in,
                                                   ushort* __restrict__ out, int n4) {
  int idx = blockIdx.x * 256 + threadIdx.x;
  int stride = gridDim.x * 256;
  for (int i = idx; i < n4; i += stride) {
    float4 v = reinterpret_cast<const float4*>(in)[i];
    ushort4 o;
    o.x = f2b(v.x); o.y = f2b(v.y); o.z = f2b(v.z); o.w = f2b(v.w);
    reinterpret_cast<ushort4*>(out)[i] = o;
  }
}

// 4 weight matrices in one launch (blockIdx.y selects), outputs contiguous
__global__ __launch_bounds__(256) void f2bf_w4(
    const float* __restrict__ w0, const float* __restrict__ w1,
    const float* __restrict__ w2, const float* __restrict__ w3,
    ushort* __restrict__ out, int n4) {
  const float* src = (blockIdx.y == 0) ? w0 : (blockIdx.y == 1) ? w1
                   : (blockIdx.y == 2) ? w2 : w3;
  ushort* dst = out + (size_t)blockIdx.y * (size_t)n4 * 4;
  int idx = blockIdx.x * 256 + threadIdx.x;
  int stride = gridDim.x * 256;
  for (int i = idx; i < n4; i += stride) {
    float4 v = reinterpret_cast<const float4*>(src)[i];
    ushort4 o;
    o.x = f2b(v.x); o.y = f2b(v.y); o.z = f2b(v.z); o.w = f2b(v.w);
    reinterpret_cast<ushort4*>(dst)[i] = o;
  }
}

// ---------------- C[i,j] = (sum_k A[i,k]*B[j,k] + bias[j]) * scale ----------------
// m97 structure: 128x128 tile, BK=32, 4 waves. Verified R0.
__global__ __launch_bounds__(256) void gemm_bt(
    const ushort* __restrict__ A,    // [M,K] bf16
    const ushort* __restrict__ B,    // [N,K] bf16
    const float*  __restrict__ bias, // [N]
    float*  __restrict__ Cf,         // fp32 out (or null)
    ushort* __restrict__ Cb,         // bf16 out (or null)
    int M, int N, int K, float scale) {
  __shared__ ushort As[128 * 32];
  __shared__ ushort Bs[128 * 32];
  const int tid  = threadIdx.x;
  const int lane = tid & 63;
  const int wave = tid >> 6;
  const int wr = (wave >> 1) << 6;
  const int wc = (wave & 1) << 6;
  const int fr  = lane & 15;
  const int fk8 = (lane >> 4) << 3;

  const size_t rowA = (size_t)blockIdx.y * 128;
  const size_t rowB = (size_t)blockIdx.x * 128;
  const ushort* Ag = A + rowA * K;
  const ushort* Bg = B + rowB * K;

  const int c0 = tid, c1 = tid + 256;
  const size_t a0 = (size_t)(c0 >> 2) * K + (size_t)((c0 & 3) << 3);
  const size_t a1 = (size_t)(c1 >> 2) * K + (size_t)((c1 & 3) << 3);

  f32x4 acc[4][4];
#pragma unroll
  for (int m = 0; m < 4; ++m)
#pragma unroll
    for (int n = 0; n < 4; ++n) acc[m][n] = fzero();

  for (int k0 = 0; k0 < K; k0 += 32) {
    __syncthreads();
    gld_lds16(Ag + a0 + k0, &As[wave * 512]);
    gld_lds16(Ag + a1 + k0, &As[2048 + wave * 512]);
    gld_lds16(Bg + a0 + k0, &Bs[wave * 512]);
    gld_lds16(Bg + a1 + k0, &Bs[2048 + wave * 512]);
    asm volatile("s_waitcnt vmcnt(0)" ::: "memory");
    __syncthreads();

    bf16x8 af[4], bfv[4];
#pragma unroll
    for (int m = 0; m < 4; ++m)
      af[m] = *reinterpret_cast<const bf16x8*>(&As[(wr + m * 16 + fr) * 32 + fk8]);
#pragma unroll
    for (int n = 0; n < 4; ++n)
      bfv[n] = *reinterpret_cast<const bf16x8*>(&Bs[(wc + n * 16 + fr) * 32 + fk8]);
#pragma unroll
    for (int m = 0; m < 4; ++m)
#pragma unroll
      for (int n = 0; n < 4; ++n)
        acc[m][n] = __builtin_amdgcn_mfma_f32_16x16x32_bf16(af[m], bfv[n], acc[m][n], 0, 0, 0);
  }

  const int orow = (lane >> 4) << 2;
#pragma unroll
  for (int m = 0; m < 4; ++m) {
#pragma unroll
    for (int n = 0; n < 4; ++n) {
      size_t gc = rowB + wc + n * 16 + fr;
      float bv = bias[gc];
#pragma unroll
      for (int r = 0; r < 4; ++r) {
        size_t gr = rowA + wr + m * 16 + orow + r;
        float v = (acc[m][n][r] + bv) * scale;
        if (Cf) Cf[gr * N + gc] = v;
        else    Cb[gr * N + gc] = f2b(v);
      }
    }
  }
}

// ---------------- fused QKV projection: B = [Wq;Wk;Wv] (3072x1024), stripe epilogue ----------------
// grid (24, 64): blockIdx.x 0-7 -> Q (scaled), 8-15 -> K, 16-23 -> V^T (j-permuted)
__global__ __launch_bounds__(256) void gemm_qkv(
    const ushort* __restrict__ A,    // [8192,1024] x bf16
    const ushort* __restrict__ Bw,   // [3072,1024] concat Wq,Wk,Wv bf16
    const float* __restrict__ bq, const float* __restrict__ bk, const float* __restrict__ bv,
    ushort* __restrict__ Qb, ushort* __restrict__ Kb, ushort* __restrict__ VbT,
    float qscale) {
  __shared__ ushort As[128 * 32];
  __shared__ ushort Bs[128 * 32];
  const int tid  = threadIdx.x;
  const int lane = tid & 63;
  const int wave = tid >> 6;
  const int wr = (wave >> 1) << 6;
  const int wc = (wave & 1) << 6;
  const int fr  = lane & 15;
  const int fk8 = (lane >> 4) << 3;
  const int K = 1024;

  const size_t rowA = (size_t)blockIdx.y * 128;
  const size_t rowB = (size_t)blockIdx.x * 128;
  const ushort* Ag = A + rowA * K;
  const ushort* Bg = Bw + rowB * K;

  const int c0 = tid, c1 = tid + 256;
  const size_t a0 = (size_t)(c0 >> 2) * K + (size_t)((c0 & 3) << 3);
  const size_t a1 = (size_t)(c1 >> 2) * K + (size_t)((c1 & 3) << 3);

  f32x4 acc[4][4];
#pragma unroll
  for (int m = 0; m < 4; ++m)
#pragma unroll
    for (int n = 0; n < 4; ++n) acc[m][n] = fzero();

  for (int k0 = 0; k0 < K; k0 += 32) {
    __syncthreads();
    gld_lds16(Ag + a0 + k0, &As[wave * 512]);
    gld_lds16(Ag + a1 + k0, &As[2048 + wave * 512]);
    gld_lds16(Bg + a0 + k0, &Bs[wave * 512]);
    gld_lds16(Bg + a1 + k0, &Bs[2048 + wave * 512]);
    asm volatile("s_waitcnt vmcnt(0)" ::: "memory");
    __syncthreads();

    bf16x8 af[4], bfv[4];
#pragma unroll
    for (int m = 0; m < 4; ++m)
      af[m] = *reinterpret_cast<const bf16x8*>(&As[(wr + m * 16 + fr) * 32 + fk8]);
#pragma unroll
    for (int n = 0; n < 4; ++n)
      bfv[n] = *reinterpret_cast<const bf16x8*>(&Bs[(wc + n * 16 + fr) * 32 + fk8]);
#pragma unroll
    for (int m = 0; m < 4; ++m)
#pragma unroll
      for (int n = 0; n < 4; ++n)
        acc[m][n] = __builtin_amdgcn_mfma_f32_16x16x32_bf16(af[m], bfv[n], acc[m][n], 0, 0, 0);
  }

  const int stripe  = blockIdx.x >> 3;            // 0=Q, 1=K, 2=V
  const int colbase = (blockIdx.x & 7) * 128;     // channel base within 1024
  const int orow = (lane >> 4) << 2;
#pragma unroll
  for (int m = 0; m < 4; ++m) {
#pragma unroll
    for (int n = 0; n < 4; ++n) {
      const int gcl = colbase + wc + n * 16 + fr;
      if (stripe == 0) {
        const float bb_ = bq[gcl];
#pragma unroll
        for (int r = 0; r < 4; ++r) {
          size_t gr = rowA + wr + m * 16 + orow + r;
          Qb[gr * 1024 + gcl] = f2b((acc[m][n][r] + bb_) * qscale);
        }
      } else if (stripe == 1) {
        const float bb_ = bk[gcl];
#pragma unroll
        for (int r = 0; r < 4; ++r) {
          size_t gr = rowA + wr + m * 16 + orow + r;
          Kb[gr * 1024 + gcl] = f2b(acc[m][n][r] + bb_);
        }
      } else {
        const float bb_ = bv[gcl];
#pragma unroll
        for (int r = 0; r < 4; ++r) {
          int tt = (int)rowA + wr + m * 16 + orow + r;   // token
          int b = tt >> 11, t = tt & 2047;
          size_t idx = (size_t)b * 2097152 + (size_t)gcl * 2048
                     + (size_t)((t & ~63) + vperm_s(t & 63));
          VbT[idx] = f2b(acc[m][n][r] + bb_);
        }
      }
    }
  }
}

// ---------------- flash attention: 8 waves, QBLK=128, KVBLK=128 ----------------
// grid (16 qtiles, 64 b*h); wave owns 16 q-rows (q-row = lane&15).
// Q pre-scaled by 0.125*log2(e) -> exp2 domain; defer-max THR=8;
// row-sum of P computed on the MFMA pipe via all-ones A operand (zacc).
__global__ __launch_bounds__(512) void attn_kernel(
    const ushort* __restrict__ Qb, const ushort* __restrict__ Kb,
    const ushort* __restrict__ VbT, ushort* __restrict__ Yb) {
  __shared__ ushort Ks[2][128 * 64];   // [128 j][8 chunk][8], chunk w holds d-chunk w^(j&7)
  __shared__ ushort Vs[2][64 * 128];   // [64 d][16 chunk][8], chunk p holds s-chunk (p&8)|((p&7)^(d&7))
  const int tid = threadIdx.x, lane = tid & 63, wave = tid >> 6;
  const int fr = lane & 15, g = lane >> 4, fk8 = g << 3;
  const int bb = blockIdx.y >> 4, h = blockIdx.y & 15;
  const size_t rowbase = (size_t)bb * 2048;
  const int cbase = h * 64;
  const ushort* Kg  = Kb  + rowbase * 1024 + cbase;
  const ushort* VgT = VbT + (size_t)bb * 2097152 + (size_t)cbase * 2048;

  // Q B-fragment: lane holds q-row i = fr, k-slots d = kk*32 + 8g + 0..7
  const int qrow = blockIdx.x * 128 + wave * 16 + fr;
  const ushort* qptr = &Qb[(rowbase + qrow) * 1024 + cbase];
  const bf16x8 qf0 = *reinterpret_cast<const bf16x8*>(qptr + fk8);
  const bf16x8 qf1 = *reinterpret_cast<const bf16x8*>(qptr + 32 + fk8);

  // staging: K tile 1024 chunks x 16B, V tile 1024 chunks; 2 each per thread
  const int rKa = tid >> 3;                       // K rows 0..63 (second: +64)
  const int wKa = (tid & 7) ^ (rKa & 7);          // (rKa+64)&7 == rKa&7
  const ushort* sK0 = Kg + (size_t)rKa * 1024 + (wKa << 3);
  const ushort* sK1 = Kg + (size_t)(rKa + 64) * 1024 + (wKa << 3);
  const int dVa = tid >> 4, pVa = tid & 15;       // V d-rows 0..31 (second: +32)
  const int qVa = (pVa & 8) | ((pVa & 7) ^ (dVa & 7));
  const ushort* sV0 = VgT + (size_t)dVa * 2048 + (qVa << 3);
  const ushort* sV1 = VgT + (size_t)(dVa + 32) * 2048 + (qVa << 3);

  f32x4 yacc[4];
#pragma unroll
  for (int nb = 0; nb < 4; ++nb) yacc[nb] = fzero();
  f32x4 zacc = fzero();                 // P row-sum accumulator (MFMA ones-trick)
  float mrow = -__builtin_inff(), lrow = 0.f;

  union { bf16x8 v; unsigned u[4]; } onesu;
#pragma unroll
  for (int i = 0; i < 4; ++i) onesu.u[i] = 0x3F803F80u;   // bf16 1.0 pairs
  const bf16x8 ones = onesu.v;
  const int ksw = (fr & 7) << 3;
  const int dsw = fr & 7;

  // prologue: stage tile 0 into buf 0
  gld_lds16(sK0, &Ks[0][wave * 512]);
  gld_lds16(sK1, &Ks[0][4096 + wave * 512]);
  gld_lds16(sV0, &Vs[0][wave * 512]);
  gld_lds16(sV1, &Vs[0][4096 + wave * 512]);
  asm volatile("s_waitcnt vmcnt(0)" ::: "memory");
  __syncthreads();

  auto tilestep = [&](const int cur, const int t) {
    if (t < 15) {   // prefetch next tile into other buffer
      const size_t oK = (size_t)(t + 1) * 131072;   // 128 rows * 1024
      const int    oV = (t + 1) * 128;              // 128 cols in [d][2048]
      gld_lds16(sK0 + oK, &Ks[cur ^ 1][wave * 512]);
      gld_lds16(sK1 + oK, &Ks[cur ^ 1][4096 + wave * 512]);
      gld_lds16(sV0 + oV, &Vs[cur ^ 1][wave * 512]);
      gld_lds16(sV1 + oV, &Vs[cur ^ 1][4096 + wave * 512]);
    }

    // S^T = K Q^T: sT[jb] reg r = S[j = 16jb + 4g + r][i = fr]
    f32x4 sT[8];
#pragma unroll
    for (int jb = 0; jb < 8; ++jb) {
      const ushort* kb_ = &Ks[cur][(jb * 16 + fr) * 64];
      bf16x8 kf0 = *reinterpret_cast<const bf16x8*>(kb_ + (fk8 ^ ksw));
      bf16x8 kf1 = *reinterpret_cast<const bf16x8*>(kb_ + ((32 + fk8) ^ ksw));
      f32x4 z = fzero();
      __builtin_amdgcn_s_setprio(1);
      z = __builtin_amdgcn_mfma_f32_16x16x32_bf16(kf0, qf0, z, 0, 0, 0);
      z = __builtin_amdgcn_mfma_f32_16x16x32_bf16(kf1, qf1, z, 0, 0, 0);
      __builtin_amdgcn_s_setprio(0);
      sT[jb] = z;
    }

    // max reduce: 4-wide ILP tree in-lane, then cross-group
    f32x4 m4 = sT[0];
#pragma unroll
    for (int jb = 1; jb < 8; ++jb)
#pragma unroll
      for (int r = 0; r < 4; ++r) m4[r] = fmaxf(m4[r], sT[jb][r]);
    float mx = fmaxf(fmaxf(m4[0], m4[1]), fmaxf(m4[2], m4[3]));
    mx = fmaxf(mx, __shfl_xor(mx, 16));
    mx = fmaxf(mx, __shfl_xor(mx, 32));

    // defer-max (T13): rescale only when max growth > 8 (P bounded by 2^8)
    if (!__all(mx <= mrow + 8.0f)) {
      const float mnew  = fmaxf(mrow, mx);
      const float alpha = __builtin_exp2f(mrow - mnew);
      lrow = (lrow + zacc[0]) * alpha;
      zacc = fzero();
#pragma unroll
      for (int nb = 0; nb < 4; ++nb)
#pragma unroll
        for (int r = 0; r < 4; ++r) yacc[nb][r] *= alpha;
      mrow = mnew;
    }

    float p[8][4];
#pragma unroll
    for (int jb = 0; jb < 8; ++jb)
#pragma unroll
      for (int r = 0; r < 4; ++r)
        p[jb][r] = __builtin_exp2f(sT[jb][r] - mrow);

    // P -> bf16 B-fragments, in-lane: pa[kk] elem f <-> j = 32kk + 16(f>>2) + 4g + (f&3)
    union { bf16x8 v; unsigned u[4]; } pa[4];
#pragma unroll
    for (int kk = 0; kk < 4; ++kk) {
      pa[kk].u[0] = pk2(p[2 * kk][0], p[2 * kk][1]);
      pa[kk].u[1] = pk2(p[2 * kk][2], p[2 * kk][3]);
      pa[kk].u[2] = pk2(p[2 * kk + 1][0], p[2 * kk + 1][1]);
      pa[kk].u[3] = pk2(p[2 * kk + 1][2], p[2 * kk + 1][3]);
    }

    // row-sum of P on the MFMA pipe: zacc[*] += sum_j P[j][fr]
    __builtin_amdgcn_s_setprio(1);
    zacc = __builtin_amdgcn_mfma_f32_16x16x32_bf16(ones, pa[0].v, zacc, 0, 0, 0);
    zacc = __builtin_amdgcn_mfma_f32_16x16x32_bf16(ones, pa[1].v, zacc, 0, 0, 0);
    zacc = __builtin_amdgcn_mfma_f32_16x16x32_bf16(ones, pa[2].v, zacc, 0, 0, 0);
    zacc = __builtin_amdgcn_mfma_f32_16x16x32_bf16(ones, pa[3].v, zacc, 0, 0, 0);
    __builtin_amdgcn_s_setprio(0);

    // Y^T += V^T P^T: A-frag slot s = 32(kk&1)+8g+f at chunk ((4kk+g)&8)|(((4kk+g)&7)^(d&7))
#pragma unroll
    for (int nb = 0; nb < 4; ++nb) {
      const int dd = (nb * 16 + fr) * 128;
      const ushort* vb_ = &Vs[cur][dd];
      bf16x8 vf0 = *reinterpret_cast<const bf16x8*>(vb_ + (((( 0 + g) & 8) | ((( 0 + g) & 7) ^ dsw)) << 3));
      bf16x8 vf1 = *reinterpret_cast<const bf16x8*>(vb_ + (((( 4 + g) & 8) | ((( 4 + g) & 7) ^ dsw)) << 3));
      bf16x8 vf2 = *reinterpret_cast<const bf16x8*>(vb_ + (((( 8 + g) & 8) | ((( 8 + g) & 7) ^ dsw)) << 3));
      bf16x8 vf3 = *reinterpret_cast<const bf16x8*>(vb_ + ((((12 + g) & 8) | (((12 + g) & 7) ^ dsw)) << 3));
      __builtin_amdgcn_s_setprio(1);
      yacc[nb] = __builtin_amdgcn_mfma_f32_16x16x32_bf16(vf0, pa[0].v, yacc[nb], 0, 0, 0);
      yacc[nb] = __builtin_amdgcn_mfma_f32_16x16x32_bf16(vf1, pa[1].v, yacc[nb], 0, 0, 0);
      yacc[nb] = __builtin_amdgcn_mfma_f32_16x16x32_bf16(vf2, pa[2].v, yacc[nb], 0, 0, 0);
      yacc[nb] = __builtin_amdgcn_mfma_f32_16x16x32_bf16(vf3, pa[3].v, yacc[nb], 0, 0, 0);
      __builtin_amdgcn_s_setprio(0);
    }

    asm volatile("s_waitcnt vmcnt(0)" ::: "memory");
    __syncthreads();
  };

  for (int t = 0; t < 16; t += 2) {   // literal cur -> compile-time LDS offsets
    tilestep(0, t);
    tilestep(1, t + 1);
  }

  // epilogue: yacc[nb] reg r = Y[row qrow][d = 16nb + 4g + r]; lane-local 1/l
  const float linv = 1.0f / (lrow + zacc[0]);
  ushort* yrow = &Yb[(rowbase + qrow) * 1024 + cbase];
#pragma unroll
  for (int nb = 0; nb < 4; ++nb) {
    ushort4 o;
    o.x = f2b(yacc[nb][0] * linv);
    o.y = f2b(yacc[nb][1] * linv);
    o.z = f2b(yacc[nb][2] * linv);
    o.w = f2b(yacc[nb][3] * linv);
    *reinterpret_cast<ushort4*>(yrow + nb * 16 + (g << 2)) = o;
  }
}

extern "C" void kernel_launch(void* const* d_in, const int* in_sizes, int n_in,
                              void* d_out, int out_size, void* d_ws, size_t ws_size,
                              hipStream_t stream) {
  const float* x  = (const float*)d_in[0];
  const float* Wq = (const float*)d_in[1];
  const float* bq = (const float*)d_in[2];
  const float* Wk = (const float*)d_in[3];
  const float* bk = (const float*)d_in[4];
  const float* Wv = (const float*)d_in[5];
  const float* bv = (const float*)d_in[6];
  const float* Wp = (const float*)d_in[7];
  const float* bp = (const float*)d_in[8];
  float* out = (float*)d_out;

  const int M = 8192, C = 1024;
  const size_t MC = (size_t)M * C, CC = (size_t)C * C;
  const size_t need = (MC * 5 + CC * 4) * sizeof(ushort);
  if (ws_size < need) return;

  ushort* xb  = (ushort*)d_ws;
  ushort* wqb = xb + MC;     // wq,wk,wv contiguous = [3072,1024] for fused QKV
  ushort* wkb = wqb + CC;
  ushort* wvb = wkb + CC;
  ushort* wpb = wvb + CC;
  ushort* Qb  = wpb + CC;
  ushort* Kb  = Qb + MC;
  ushort* VbT = Kb + MC;     // [4][1024][2048] transposed, j-permuted
  ushort* Yb  = VbT + MC;
  (void)wkb; (void)wvb;

  f2bf_kernel<<<2048, 256, 0, stream>>>(x, xb, (int)(MC / 4));
  f2bf_w4<<<dim3(256, 4), 256, 0, stream>>>(Wq, Wk, Wv, Wp, wqb, (int)(CC / 4));

  const float QSCALE = 0.18033688011112042f;  // 0.125 * log2(e): softmax in exp2 domain
  gemm_qkv<<<dim3(24, 64), 256, 0, stream>>>(xb, wqb, bq, bk, bv, Qb, Kb, VbT, QSCALE);

  attn_kernel<<<dim3(16, 64), 512, 0, stream>>>(Qb, Kb, VbT, Yb);

  gemm_bt<<<dim3(8, 64), 256, 0, stream>>>(Yb, wpb, bp, out, nullptr, M, C, C, 1.0f);
}